// Round 5
// baseline (205.194 us; speedup 1.0000x reference)
//
#include <hip/hip_runtime.h>

// SimpleRNN fused kernel for MI355X (gfx950).  B=32768, T=28, I=28, H=128, C=10.
//
// Transposed recurrence D[h][b] = W * S^T:
//   A-operand = W (m=h_out) resident in VGPRs; B-operand = S^T from LDS
//   (k=h_in contiguous per lane); D rows (4 consecutive h) pack to b64 writes
//   of row-major S[b][h] -> no transpose between steps.
// MFMA 16x16x32 bf16 layouts (m89/m91/m120):
//   A: A[m=lane&15][k=(lane>>4)*8+j]   B: B[k=(lane>>4)*8+j][n=lane&15]
//   D: D[(lane>>4)*4+reg][lane&15]
//
// R5 (R4 was 95.7us, 5.37M LDS bank conflicts, VALUBusy 55% = 52.6us floor):
//  - LDS back to stride 132 + b64-pair reads (R1/R3 measured ZERO conflicts;
//    the 136/b128 combo of R4 cost ~6 extra cyc per read).
//  - tanh Pade(5,4) computed in PACKED fp32 via inline-asm v_pk_{mul,add,fma}_f32
//    (compiler was emitting scalar VALU), one v_rcp per 4 elements via the
//    combined-reciprocal trick, med3 clamp retained.
//  - keep R4's x software pipeline + bias-as-MFMA-C.
// Grid 1024 x 256thr = 4 blocks/CU (16 waves/CU), launch_bounds(256,4).

#define T_STEPS 28
#define I_DIM   28
#define S_STRIDE 132

typedef __attribute__((ext_vector_type(2))) float f32x2;
typedef __attribute__((ext_vector_type(4))) float f32x4;
typedef __attribute__((ext_vector_type(8))) short short8;

#define MFMA16 __builtin_amdgcn_mfma_f32_16x16x32_bf16

__device__ __forceinline__ f32x2 pk_mul(f32x2 a, f32x2 b) {
  f32x2 d; asm("v_pk_mul_f32 %0, %1, %2" : "=v"(d) : "v"(a), "v"(b)); return d;
}
__device__ __forceinline__ f32x2 pk_add(f32x2 a, f32x2 b) {
  f32x2 d; asm("v_pk_add_f32 %0, %1, %2" : "=v"(d) : "v"(a), "v"(b)); return d;
}
__device__ __forceinline__ f32x2 pk_fma(f32x2 a, f32x2 b, f32x2 c) {
  f32x2 d; asm("v_pk_fma_f32 %0, %1, %2, %3" : "=v"(d) : "v"(a), "v"(b), "v"(c)); return d;
}

__device__ __forceinline__ unsigned pack2(float lo, float hi) {
#if __has_builtin(__builtin_amdgcn_cvt_pk_bf16_f32)
  auto p = __builtin_amdgcn_cvt_pk_bf16_f32(lo, hi);   // RNE pack
  return __builtin_bit_cast(unsigned, p);
#else
  unsigned a = __builtin_bit_cast(unsigned, lo);
  a += 0x7FFFu + ((a >> 16) & 1u);
  unsigned b = __builtin_bit_cast(unsigned, hi);
  b += 0x7FFFu + ((b >> 16) & 1u);
  return (a >> 16) | (b & 0xFFFF0000u);
#endif
}

__device__ __forceinline__ float bf2f(unsigned short s) {
  return __builtin_bit_cast(float, (unsigned)s << 16);
}

__device__ __forceinline__ short8 to_frag(f32x4 a, f32x4 b) {
  union { unsigned u[4]; short8 v; } r;
  r.u[0] = pack2(a[0], a[1]);
  r.u[1] = pack2(a[2], a[3]);
  r.u[2] = pack2(b[0], b[1]);
  r.u[3] = pack2(b[2], b[3]);
  return r.v;
}

__device__ __forceinline__ short8 load_sfrag(const unsigned short* sp, int off) {
  // two b64 reads at stride-132 rows: measured conflict-free (R1/R3)
  union { uint2 d[2]; short8 v; } r;
  r.d[0] = *(const uint2*)(sp + off);
  r.d[1] = *(const uint2*)(sp + off + 4);
  return r.v;
}

// Pade(5,4) tanh on 4 elements, packed-fp32 math + single combined rcp.
// t = z(945 + 105 z^2 + z^4) / (945 + 420 z^2 + 15 z^4), max err ~1.2e-3,
// den >= 945 so products (<= ~2e16) are finite; med3 clamps the tail.
__device__ __forceinline__ f32x4 tanh4(f32x4 z, f32x2 c945, f32x2 c105,
                                       f32x2 c420, f32x2 c15) {
  f32x2 z0 = {z[0], z[1]}, z1 = {z[2], z[3]};
  f32x2 x0 = pk_mul(z0, z0), x1 = pk_mul(z1, z1);
  f32x2 p0 = pk_fma(x0, pk_add(x0, c105), c945);
  f32x2 p1 = pk_fma(x1, pk_add(x1, c105), c945);
  f32x2 q0 = pk_fma(x0, pk_fma(x0, c15, c420), c945);
  f32x2 q1 = pk_fma(x1, pk_fma(x1, c15, c420), c945);
  f32x2 n0 = pk_mul(z0, p0), n1 = pk_mul(z1, p1);
  // combined reciprocal: 1 transcendental for 4 denominators
  float s01 = q0[0] * q0[1], s23 = q1[0] * q1[1];
  float r = __builtin_amdgcn_rcpf(s01 * s23);
  float r01 = r * s23, r23 = r * s01;        // 1/(q0*q1), 1/(q2*q3)
  f32x2 i0 = {r01 * q0[1], r01 * q0[0]};     // (1/q0, 1/q1)
  f32x2 i1 = {r23 * q1[1], r23 * q1[0]};
  f32x2 t0 = pk_mul(n0, i0), t1 = pk_mul(n1, i1);
  f32x4 out;
  out[0] = __builtin_amdgcn_fmed3f(t0[0], -1.0f, 1.0f);
  out[1] = __builtin_amdgcn_fmed3f(t0[1], -1.0f, 1.0f);
  out[2] = __builtin_amdgcn_fmed3f(t1[0], -1.0f, 1.0f);
  out[3] = __builtin_amdgcn_fmed3f(t1[1], -1.0f, 1.0f);
  return out;
}

__global__ __launch_bounds__(256, 4) void rnn_fused(
    const float* __restrict__ x,  const float* __restrict__ Uw,
    const float* __restrict__ Ub, const float* __restrict__ Ww,
    const float* __restrict__ Wb, const float* __restrict__ Vw,
    const float* __restrict__ Vb, float* __restrict__ out) {
  __shared__ __align__(16) unsigned short Sbuf[2][32 * S_STRIDE];

  const int tid  = threadIdx.x;
  const int w    = tid >> 6;
  const int lane = tid & 63;
  const int l15  = lane & 15;
  const int q    = lane >> 4;           // 0..3
  const int mrow = w * 32;              // h base for this wave (2 m-tiles)
  const int b0   = blockIdx.x * 32;

  const f32x4 zero4 = {0.f, 0.f, 0.f, 0.f};
  const f32x2 c945 = {945.f, 945.f}, c105 = {105.f, 105.f};
  const f32x2 c420 = {420.f, 420.f}, c15  = {15.f, 15.f};

  // ---- persistent register fragments ----
  short8 wfrag[2][4];   // [mt][kt]  32 VGPR
  short8 ufrag[2];      // [mt], K=32 padded (k>=28 zeroed => B garbage annihilated)
  f32x4  bias[2];       // Ub[h]+Wb[h] at D rows h = mrow + mt*16 + q*4 + r
#pragma unroll
  for (int mt = 0; mt < 2; ++mt) {
    const int h = mrow + mt * 16 + l15;
    const float* wp = Ww + h * 128 + q * 8;
#pragma unroll
    for (int kt = 0; kt < 4; ++kt) {
      wfrag[mt][kt] = to_frag(*(const f32x4*)wp, *(const f32x4*)(wp + 4));
      wp += 32;
    }
    const float* up = Uw + h * I_DIM + q * 8;
    f32x4 u0 = *(const f32x4*)up;
    f32x4 u1 = zero4;
    if (q < 3) u1 = *(const f32x4*)(up + 4);
    ufrag[mt] = to_frag(u0, u1);
    const int hb = mrow + mt * 16 + q * 4;
    bias[mt] = *(const f32x4*)(Wb + hb) + *(const f32x4*)(Ub + hb);
  }

  // x B-operand frags: n = batch = nt*16 + lane&15, k = i = q*8+j.
  // q==3 hi-half reads a valid in-row address; annihilated by zeroed U cols.
  const float* xlo[2];
  const float* xhi[2];
#pragma unroll
  for (int nt = 0; nt < 2; ++nt) {
    const float* base = x + (size_t)(b0 + nt * 16 + l15) * (T_STEPS * I_DIM);
    xlo[nt] = base + q * 8;
    xhi[nt] = base + ((q < 3) ? q * 8 + 4 : 0);
  }

  int ro[2];
#pragma unroll
  for (int nt = 0; nt < 2; ++nt) ro[nt] = (nt * 16 + l15) * S_STRIDE;

  f32x4 acc[2][2];   // [mt][nt]
  short8 xf0, xf1;   // x frags for the CURRENT step (pipelined)

  // ---- t = 0 (S=0: projection only) + prefetch x(1) ----
  {
    f32x4 xa0 = *(const f32x4*)xlo[0], xb0 = *(const f32x4*)xhi[0];
    f32x4 xa1 = *(const f32x4*)xlo[1], xb1 = *(const f32x4*)xhi[1];
    xlo[0] += I_DIM; xhi[0] += I_DIM; xlo[1] += I_DIM; xhi[1] += I_DIM;
    f32x4 pa0 = *(const f32x4*)xlo[0], pb0 = *(const f32x4*)xhi[0];
    f32x4 pa1 = *(const f32x4*)xlo[1], pb1 = *(const f32x4*)xhi[1];

    xf0 = to_frag(xa0, xb0); xf1 = to_frag(xa1, xb1);
    unsigned short* wp = &Sbuf[1][0];
#pragma unroll
    for (int mt = 0; mt < 2; ++mt) {
      f32x4 d0 = MFMA16(ufrag[mt], xf0, bias[mt], 0, 0, 0);
      f32x4 d1 = MFMA16(ufrag[mt], xf1, bias[mt], 0, 0, 0);
      f32x4 t0 = tanh4(d0, c945, c105, c420, c15);
      f32x4 t1 = tanh4(d1, c945, c105, c420, c15);
      uint2 dd0; dd0.x = pack2(t0[0], t0[1]); dd0.y = pack2(t0[2], t0[3]);
      uint2 dd1; dd1.x = pack2(t1[0], t1[1]); dd1.y = pack2(t1[2], t1[3]);
      *(uint2*)(wp + ro[0] + mrow + mt * 16 + q * 4) = dd0;
      *(uint2*)(wp + ro[1] + mrow + mt * 16 + q * 4) = dd1;
    }
    xf0 = to_frag(pa0, pb0); xf1 = to_frag(pa1, pb1);
  }
  __syncthreads();

  // ---- t = 1 .. 27 ----
#pragma unroll 1
  for (int t = 1; t < T_STEPS; ++t) {
    // issue x(t+1) loads FIRST (consumed at end of this step)
    f32x4 pa0, pb0, pa1, pb1;
    const bool more = (t < T_STEPS - 1);
    if (more) {
      xlo[0] += I_DIM; xhi[0] += I_DIM; xlo[1] += I_DIM; xhi[1] += I_DIM;
      pa0 = *(const f32x4*)xlo[0]; pb0 = *(const f32x4*)xhi[0];
      pa1 = *(const f32x4*)xlo[1]; pb1 = *(const f32x4*)xhi[1];
    }

    const unsigned short* sp = &Sbuf[t & 1][0];
    const unsigned short* spA = sp + ro[0] + q * 8;
    const unsigned short* spB = sp + ro[1] + q * 8;

    // kt = 0: bias as C-operand (no acc init)
    short8 sA = load_sfrag(spA, 0);
    short8 sB = load_sfrag(spB, 0);
#pragma unroll
    for (int mt = 0; mt < 2; ++mt) {
      acc[mt][0] = MFMA16(wfrag[mt][0], sA, bias[mt], 0, 0, 0);
      acc[mt][1] = MFMA16(wfrag[mt][0], sB, bias[mt], 0, 0, 0);
    }
#pragma unroll
    for (int kt = 1; kt < 4; ++kt) {
      sA = load_sfrag(spA, kt * 32);
      sB = load_sfrag(spB, kt * 32);
#pragma unroll
      for (int mt = 0; mt < 2; ++mt) {
        acc[mt][0] = MFMA16(wfrag[mt][kt], sA, acc[mt][0], 0, 0, 0);
        acc[mt][1] = MFMA16(wfrag[mt][kt], sB, acc[mt][1], 0, 0, 0);
      }
    }
#pragma unroll
    for (int mt = 0; mt < 2; ++mt) {
      acc[mt][0] = MFMA16(ufrag[mt], xf0, acc[mt][0], 0, 0, 0);
      acc[mt][1] = MFMA16(ufrag[mt], xf1, acc[mt][1], 0, 0, 0);
    }

    unsigned short* wp = &Sbuf[(t + 1) & 1][0];
#pragma unroll
    for (int mt = 0; mt < 2; ++mt)
#pragma unroll
      for (int nt = 0; nt < 2; ++nt) {
        f32x4 th = tanh4(acc[mt][nt], c945, c105, c420, c15);
        uint2 dd; dd.x = pack2(th[0], th[1]); dd.y = pack2(th[2], th[3]);
        *(uint2*)(wp + ro[nt] + mrow + mt * 16 + q * 4) = dd;
      }

    if (more) { xf0 = to_frag(pa0, pb0); xf1 = to_frag(pa1, pb1); }
    __syncthreads();
  }

  // ---- epilogue: out[b][c] = sum_h S[b][h]*Vw[c][h] + Vb[c] ----
  // Final S is in Sbuf[(27+1)&1] = Sbuf[0]. 32 rows x 10 cols per block.
  {
    const unsigned short* sf = &Sbuf[0][0];
    const int r  = tid >> 3;        // 0..31
    const int c0 = tid & 7;         // col c0; threads with c0<2 also do c0+8
    const float* v0 = Vw + c0 * 128;
    const float* v1 = Vw + ((c0 & 1) + 8) * 128;
    const unsigned short* srow = sf + r * S_STRIDE;
    float a0 = 0.f, a1 = 0.f;
#pragma unroll 8
    for (int h = 0; h < 128; ++h) {
      float s = bf2f(srow[h]);
      a0 += s * v0[h];
      a1 += s * v1[h];
    }
    float* op = out + (size_t)(b0 + r) * 10;
    op[c0] = a0 + Vb[c0];
    if (c0 < 2) op[c0 + 8] = a1 + Vb[(c0 & 1) + 8];
  }
}

extern "C" void kernel_launch(void* const* d_in, const int* in_sizes, int n_in,
                              void* d_out, int out_size, void* d_ws, size_t ws_size,
                              hipStream_t stream) {
  const float* x  = (const float*)d_in[0];
  const float* Uw = (const float*)d_in[1];
  const float* Ub = (const float*)d_in[2];
  const float* Ww = (const float*)d_in[3];
  const float* Wb = (const float*)d_in[4];
  const float* Vw = (const float*)d_in[5];
  const float* Vb = (const float*)d_in[6];
  rnn_fused<<<1024, 256, 0, stream>>>(x, Uw, Ub, Ww, Wb, Vw, Vb, (float*)d_out);
}